// Round 24
// baseline (107.187 us; speedup 1.0000x reference)
//
#include <hip/hip_runtime.h>
#include <hip/hip_bf16.h>

#define NHEADS 12
#define NFRAMES 8
#define NTOK 1568
#define CDIM 768
#define DHEAD 64
#define BATCH 2
#define MROWS (BATCH * NTOK) /* 3136 */
#define MPAD 3200
#define K3 (3 * CDIM)        /* 2304 */
#define AREA1 197
#define TPF 196
#define LOG2E 1.4426950408889634f

typedef __bf16 bf16x8 __attribute__((ext_vector_type(8)));
typedef float f32x4 __attribute__((ext_vector_type(4)));
typedef float f32x16 __attribute__((ext_vector_type(16)));
typedef unsigned short u16x8 __attribute__((ext_vector_type(8)));

#if __has_builtin(__builtin_amdgcn_exp2f)
#define EXP2(x) __builtin_amdgcn_exp2f(x)
#else
#define EXP2(x) exp2f(x)
#endif

__device__ __forceinline__ unsigned short f2bf(float f) {
  return __builtin_bit_cast(unsigned short, (__bf16)f);
}
__device__ __forceinline__ float bf2f(unsigned short u) {
  unsigned int x = ((unsigned int)u) << 16;
  return __builtin_bit_cast(float, x);
}
__device__ __forceinline__ bf16x8 ld8(const unsigned short* p) {
  return __builtin_bit_cast(bf16x8, *(const u16x8*)p);
}
__device__ __forceinline__ f32x4 mfma16(bf16x8 a, bf16x8 b, f32x4 c) {
  return __builtin_amdgcn_mfma_f32_16x16x32_bf16(a, b, c, 0, 0, 0);
}
__device__ __forceinline__ f32x16 mfma32(bf16x8 a, bf16x8 b, f32x16 c) {
  return __builtin_amdgcn_mfma_f32_32x32x16_bf16(a, b, c, 0, 0, 0);
}
__device__ __forceinline__ unsigned int pack2(float lo, float hi) {
  return ((unsigned int)f2bf(hi) << 16) | (unsigned int)f2bf(lo);
}
__device__ __forceinline__ void swap32(unsigned int a, unsigned int b,
                                       unsigned int& x, unsigned int& y) {
#if __has_builtin(__builtin_amdgcn_permlane32_swap)
  auto r = __builtin_amdgcn_permlane32_swap(a, b, false, false);
  x = r[0]; y = r[1];
#else
  const bool hi = (threadIdx.x & 63) >= 32;
  unsigned int ea = (unsigned int)__shfl_xor((int)a, 32);
  unsigned int eb = (unsigned int)__shfl_xor((int)b, 32);
  x = hi ? eb : a;
  y = hi ? b : ea;
#endif
}
#define GL_LDS(src, dst)                                                    \
  __builtin_amdgcn_global_load_lds(                                         \
      (const __attribute__((address_space(1))) void*)(src),                 \
      (__attribute__((address_space(3))) void*)(dst), 16, 0, 0)

// m204 bijective XCD swizzle for arbitrary nwg
__device__ __forceinline__ int xcd_swz(int lin, int nwg) {
  const int q = nwg >> 3, r = nwg & 7;
  const int xcd = lin & 7, idx = lin >> 3;
  return (xcd < r ? xcd * (q + 1) : r * (q + 1) + (xcd - r) * q) + idx;
}

// ---------------- gemm0 (qkv proj) BK=64 + fused biasP tail (R23, frozen) --------
__global__ __launch_bounds__(512) void gemm0_kernel(
    const float* __restrict__ x,
    const float* __restrict__ qkv_w,
    const float* __restrict__ q_bias,
    const float* __restrict__ v_bias,
    unsigned short* __restrict__ qbuf,
    unsigned short* __restrict__ kbuf,
    unsigned short* __restrict__ vtbuf,
    const float* __restrict__ rpt,
    const int* __restrict__ rpi,
    const float* __restrict__ rtt,
    const int* __restrict__ rti,
    unsigned short* __restrict__ biasP,
    float* __restrict__ bias2) {
  __shared__ __align__(16) char smem[65536];
  unsigned short* As = (unsigned short*)smem;
  unsigned short* Bs = As + 16384;

  if (blockIdx.x >= 450) {  // ---- fused biasP tail ----
    const int bb = blockIdx.x - 450;
    if (bb == NHEADS * AREA1) {
      for (int t = threadIdx.x; t < NHEADS * 64; t += 512) {
        int h = t >> 6, ff = t & 63;
        bias2[t] = rtt[rti[ff] * NHEADS + h] * LOG2E;
      }
      return;
    }
    float* row = (float*)smem;
    const int h = bb / AREA1;
    const int i = bb - h * AREA1;  // qmod
    for (int j = threadIdx.x; j < AREA1; j += 512)
      row[j] = rpt[rpi[i * AREA1 + j] * NHEADS + h] * LOG2E;
    __syncthreads();
    unsigned short* dst = biasP + (size_t)bb * 49 * 32;
    for (int e = threadIdx.x; e < 49 * 32; e += 512) {
      const int t = e >> 5, r = e & 31;
      const int hi = r >> 4, rr = r & 15;
      int km = 32 * t + (rr & 3) + 8 * (rr >> 2) + 4 * hi;
      km %= AREA1;
      dst[e] = f2bf(row[km]);
    }
    return;
  }

  // ---- gemm body ----
  const int lane = threadIdx.x & 63;
  const int wv = threadIdx.x >> 6;  // 0..7
  const int tid = threadIdx.x;
  const int wg = xcd_swz(blockIdx.x, 450);
  const int m0 = (wg / 18) * 128;
  const int n0 = (wg % 18) * 128;

  const int srow = tid >> 3;
  const int srcc = (tid & 7) ^ ((tid >> 3) & 7);
  int ar0 = m0 + srow;      if (ar0 >= MROWS) ar0 = MROWS - 1;
  int ar1 = m0 + 64 + srow; if (ar1 >= MROWS) ar1 = MROWS - 1;
  const int br0 = n0 + srow, br1 = n0 + 64 + srow;

  f32x4 ra[4], rb[4];
  auto issueLoads = [&](int kt) {
    const int k0 = kt * 64 + srcc * 8;
    const f32x4* p;
    p = (const f32x4*)(x + (size_t)ar0 * CDIM + k0);     ra[0] = p[0]; ra[1] = p[1];
    p = (const f32x4*)(x + (size_t)ar1 * CDIM + k0);     ra[2] = p[0]; ra[3] = p[1];
    p = (const f32x4*)(qkv_w + (size_t)br0 * CDIM + k0); rb[0] = p[0]; rb[1] = p[1];
    p = (const f32x4*)(qkv_w + (size_t)br1 * CDIM + k0); rb[2] = p[0]; rb[3] = p[1];
  };
  auto cvt8 = [&](const f32x4& a, const f32x4& b) {
    u16x8 w;
    w[0] = f2bf(a[0]); w[1] = f2bf(a[1]); w[2] = f2bf(a[2]); w[3] = f2bf(a[3]);
    w[4] = f2bf(b[0]); w[5] = f2bf(b[1]); w[6] = f2bf(b[2]); w[7] = f2bf(b[3]);
    return w;
  };
  auto writeStage = [&](int buf) {
    const int o = buf * 8192 + (tid >> 3) * 64 + (tid & 7) * 8;
    *(u16x8*)&As[o]        = cvt8(ra[0], ra[1]);
    *(u16x8*)&As[o + 4096] = cvt8(ra[2], ra[3]);
    *(u16x8*)&Bs[o]        = cvt8(rb[0], rb[1]);
    *(u16x8*)&Bs[o + 4096] = cvt8(rb[2], rb[3]);
  };

  f32x4 acc[2][4] = {};
  const int rbase = (wv & 3) * 32;
  const int cbase = (wv >> 2) * 64;
  const int lc = lane >> 4;

  issueLoads(0);
  __builtin_amdgcn_sched_barrier(0);
  writeStage(0);
  __syncthreads();
  int cur = 0;
  for (int kt = 0; kt < CDIM / 64; ++kt) {
    if (kt + 1 < CDIM / 64) issueLoads(kt + 1);
    __builtin_amdgcn_sched_barrier(0);
#pragma unroll
    for (int s = 0; s < 2; ++s) {
      const int c = s * 4 + lc;
      bf16x8 af[2], bg[4];
#pragma unroll
      for (int i = 0; i < 2; ++i) {
        const int rr = rbase + i * 16 + (lane & 15);
        af[i] = ld8(&As[cur * 8192 + rr * 64 + ((c ^ (rr & 7)) << 3)]);
      }
#pragma unroll
      for (int j = 0; j < 4; ++j) {
        const int rr = cbase + j * 16 + (lane & 15);
        bg[j] = ld8(&Bs[cur * 8192 + rr * 64 + ((c ^ (rr & 7)) << 3)]);
      }
#pragma unroll
      for (int i = 0; i < 2; ++i)
#pragma unroll
        for (int j = 0; j < 4; ++j)
          acc[i][j] = mfma16(af[i], bg[j], acc[i][j]);
    }
    if (kt + 1 < CDIM / 64) writeStage(cur ^ 1);
    __syncthreads();
    cur ^= 1;
  }

#pragma unroll
  for (int i = 0; i < 2; ++i) {
#pragma unroll
    for (int j = 0; j < 4; ++j) {
#pragma unroll
      for (int r = 0; r < 4; ++r) {
        int grow = m0 + rbase + i * 16 + (lane >> 4) * 4 + r;
        int gcol = n0 + cbase + j * 16 + (lane & 15);
        if (grow >= MROWS) continue;
        float v = acc[i][j][r];
        int which = gcol / CDIM;
        int cc = gcol - which * CDIM;
        int hh = cc >> 6, dd = cc & 63;
        int b = grow / NTOK, n = grow - b * NTOK;
        size_t hd = ((size_t)(b * NHEADS + hh) * NTOK + n) * 64 + dd;
        if (which == 0)
          qbuf[hd] = f2bf((v + q_bias[cc]) * (0.125f * LOG2E));
        else if (which == 1)
          kbuf[hd] = f2bf(v);
        else
          vtbuf[((size_t)(b * NHEADS + hh) * 64 + dd) * NTOK + n] =
              f2bf(v + v_bias[cc]);
      }
    }
  }
}

// ---------------- BM x BN MFMA GEMM template (gemm1 / MODE1 only; R22 frozen) -----
template <int MODE, int BM, int BN, int TPB, int WAVES_M, int NB_N>
__global__ __launch_bounds__(TPB) void gemm_kernel(
    const float* __restrict__ Afp,
    const unsigned short* __restrict__ Abf,
    const float* __restrict__ Bfp,
    const float* __restrict__ bias0,
    const float* __restrict__ biasv,
    unsigned short* __restrict__ qbuf,
    unsigned short* __restrict__ kbuf,
    unsigned short* __restrict__ vtbuf,
    float* __restrict__ Cout) {
  constexpr int WAVES = TPB / 64;
  constexpr int WAVES_N = WAVES / WAVES_M;
  constexpr int WM = BM / WAVES_M;
  constexpr int WN = BN / WAVES_N;
  static_assert(BM * 4 == TPB && BN * 4 == TPB, "one chunk per thread");
  __shared__ unsigned short As[2][BM * 32];
  __shared__ unsigned short Bs[2][BN * 32];
  const int lane = threadIdx.x & 63;
  const int wv = threadIdx.x >> 6;
  const int tid = threadIdx.x;
  const int wg = xcd_swz(blockIdx.x, gridDim.x);
  const int m0 = (wg / NB_N) * BM;
  const int n0 = (wg % NB_N) * BN;

  const int srow = tid >> 2;
  const int srcc = (tid & 3) ^ ((tid >> 3) & 3);
  int arow = m0 + srow; if (arow >= MROWS) arow = MROWS - 1;
  const int brow = n0 + srow;

  f32x4 ra0, ra1, rb0, rb1;
  auto issueLoads = [&](int kt, int buf) {
    const int k0 = kt * 32 + srcc * 8;
    if (MODE == 0) {
      const f32x4* ap = (const f32x4*)(Afp + (size_t)arow * CDIM + k0);
      ra0 = ap[0]; ra1 = ap[1];
    } else {
      GL_LDS(Abf + (size_t)arow * CDIM + k0, &As[buf][tid * 8]);
    }
    const f32x4* bp = (const f32x4*)(Bfp + (size_t)brow * CDIM + k0);
    rb0 = bp[0]; rb1 = bp[1];
  };
  auto writeStage = [&](int buf) {
    u16x8 w;
    if (MODE == 0) {
      w[0] = f2bf(ra0[0]); w[1] = f2bf(ra0[1]); w[2] = f2bf(ra0[2]);
      w[3] = f2bf(ra0[3]); w[4] = f2bf(ra1[0]); w[5] = f2bf(ra1[1]);
      w[6] = f2bf(ra1[2]); w[7] = f2bf(ra1[3]);
      *(u16x8*)&As[buf][tid * 8] = w;
    }
    w[0] = f2bf(rb0[0]); w[1] = f2bf(rb0[1]); w[2] = f2bf(rb0[2]);
    w[3] = f2bf(rb0[3]); w[4] = f2bf(rb1[0]); w[5] = f2bf(rb1[1]);
    w[6] = f2bf(rb1[2]); w[7] = f2bf(rb1[3]);
    *(u16x8*)&Bs[buf][tid * 8] = w;
  };

  f32x4 acc[WM / 16][WN / 16] = {};
  const int rbase = (wv & (WAVES_M - 1)) * WM;
  const int cbase = (wv / WAVES_M) * WN;
  const int lc = lane >> 4;

  issueLoads(0, 0);
  __builtin_amdgcn_sched_barrier(0);
  writeStage(0);
  __syncthreads();
  int cur = 0;
  for (int kt = 0; kt < CDIM / 32; ++kt) {
    if (kt + 1 < CDIM / 32) issueLoads(kt + 1, cur ^ 1);
    __builtin_amdgcn_sched_barrier(0);
    bf16x8 af[WM / 16], bg[WN / 16];
#pragma unroll
    for (int i = 0; i < WM / 16; ++i) {
      const int ra = rbase + i * 16 + (lane & 15);
      af[i] = ld8(&As[cur][ra * 32 + ((lc ^ ((ra >> 1) & 3)) << 3)]);
    }
#pragma unroll
    for (int j = 0; j < WN / 16; ++j) {
      const int rb = cbase + j * 16 + (lane & 15);
      bg[j] = ld8(&Bs[cur][rb * 32 + ((lc ^ ((rb >> 1) & 3)) << 3)]);
    }
#pragma unroll
    for (int i = 0; i < WM / 16; ++i)
#pragma unroll
      for (int j = 0; j < WN / 16; ++j)
        acc[i][j] = mfma16(af[i], bg[j], acc[i][j]);
    if (kt + 1 < CDIM / 32) writeStage(cur ^ 1);
    __syncthreads();
    cur ^= 1;
  }

#pragma unroll
  for (int i = 0; i < WM / 16; ++i) {
#pragma unroll
    for (int j = 0; j < WN / 16; ++j) {
#pragma unroll
      for (int r = 0; r < 4; ++r) {
        int grow = m0 + rbase + i * 16 + (lane >> 4) * 4 + r;
        int gcol = n0 + cbase + j * 16 + (lane & 15);
        if (grow >= MROWS) continue;
        float v = acc[i][j][r];
        if (MODE == 0) {
          int which = gcol / CDIM;
          int cc = gcol - which * CDIM;
          int hh = cc >> 6, dd = cc & 63;
          int b = grow / NTOK, n = grow - b * NTOK;
          size_t hd = ((size_t)(b * NHEADS + hh) * NTOK + n) * 64 + dd;
          if (which == 0)
            qbuf[hd] = f2bf((v + bias0[cc]) * (0.125f * LOG2E));
          else if (which == 1)
            kbuf[hd] = f2bf(v);
          else
            vtbuf[((size_t)(b * NHEADS + hh) * 64 + dd) * NTOK + n] =
                f2bf(v + biasv[cc]);
        } else {
          Cout[(size_t)grow * CDIM + gcol] = v + bias0[gcol];
        }
      }
    }
  }
}

// ---------------- flash attention: R15 loop + two-phase merge -> LDS 32768 --------
// R24: smem 36864 -> 32768 via R16's two-phase merge ([4][64][17] f32 = 17KB
// unioned with the 32KB staging). 160/32 = 5 blocks/CU (was 4): all 1176 blocks
// co-resident (5*256=1280), eliminating the 0.59-block makespan tail, and
// VGPR=88 permits the 5th wave/SIMD (88*5=440<=512). Loop body byte-identical.
__global__ __launch_bounds__(256) void attn_kernel(
    const unsigned short* __restrict__ qbuf,
    const unsigned short* __restrict__ kbuf,
    const unsigned short* __restrict__ vtbuf,
    const unsigned short* __restrict__ biasP,
    const float* __restrict__ bias2,
    unsigned short* __restrict__ aout) {
  __shared__ __align__(16) char smem[32768];
  unsigned short* stg = (unsigned short*)smem;
  float* mb = (float*)smem;

  const int lane = threadIdx.x & 63;
  const int wv = threadIdx.x >> 6;
  const int wu = (blockIdx.x & 7) * 147 + (blockIdx.x >> 3);
  const int bh = wu / 49;
  const int qt = wu - bh * 49;
  const int q0 = qt * 32;
  const int h = bh % NHEADS;
  const int b = bh / NHEADS;
  const int qlane = lane & 31;
  const int hi = lane >> 5;
  const int hi4 = hi * 4;
  const int qn = q0 + qlane;
  const int qfr = qn / TPF < 7 ? qn / TPF : 7;
  const int qmod = qn % AREA1;

  const unsigned short* qp = qbuf + (size_t)bh * NTOK * DHEAD;
  const unsigned short* kp = kbuf + (size_t)bh * NTOK * DHEAD;
  const unsigned short* vp = vtbuf + (size_t)bh * DHEAD * NTOK;
  const unsigned short* bP = biasP + ((size_t)(h * AREA1 + qmod) * 49) * 32 + hi * 16;
  const float* b2q = bias2 + h * 64 + qfr * 8;

  unsigned short* KsW = stg + wv * 4096;
  unsigned short* VsW = KsW + 2048;

  const unsigned short* ksb =
      kp + (size_t)(lane >> 3) * DHEAD + (((lane & 7) ^ (lane >> 3)) << 3);
  const unsigned short* vsb =
      vp + (size_t)(lane >> 2) * NTOK + (((lane & 3) ^ ((lane >> 3) & 3)) << 3);

  auto stage = [&](int gt) {
    const int kv0 = gt * 32;
#pragma unroll
    for (int j = 0; j < 4; ++j) {
      GL_LDS(ksb + (size_t)(kv0 + j * 8) * DHEAD, KsW + j * 512);
      GL_LDS(vsb + kv0 + (size_t)(j * 16) * NTOK, VsW + j * 512);
    }
  };

  bf16x8 aq[4];
#pragma unroll
  for (int c = 0; c < 4; ++c)
    aq[c] = ld8(qp + (size_t)qn * DHEAD + c * 16 + hi * 8);

  f32x16 o0 = {}, o1 = {};
  float lrun = 0.f;

  stage(wv);
  u16x8 ubA, ubB;
  {
    const u16x8* bp = (const u16x8*)(bP + (size_t)wv * 32);
    ubA = bp[0]; ubB = bp[1];
  }
  int kfl = 0;
  float b2lo = b2q[0], b2hi = b2q[1];
  const int skey = qlane & 7;
  const int vswz = (qlane >> 1) & 3;

  for (int gt = wv; gt < 49; gt += 4) {
    asm volatile("s_waitcnt vmcnt(0)" ::: "memory");
    __builtin_amdgcn_sched_barrier(0);
    bf16x8 kf[4];
#pragma unroll
    for (int c = 0; c < 4; ++c)
      kf[c] = ld8(&KsW[qlane * 64 + ((((c << 1) + hi) ^ skey) << 3)]);
    bf16x8 vf0 = ld8(&VsW[qlane * 32 + ((hi ^ vswz) << 3)]);
    bf16x8 vf1 = ld8(&VsW[qlane * 32 + (((2 + hi) ^ vswz) << 3)]);
    bf16x8 vf2 = ld8(&VsW[(32 + qlane) * 32 + ((hi ^ vswz) << 3)]);
    bf16x8 vf3 = ld8(&VsW[(32 + qlane) * 32 + (((2 + hi) ^ vswz) << 3)]);
    asm volatile("s_waitcnt lgkmcnt(0)" ::: "memory");
    __builtin_amdgcn_sched_barrier(0);
    const bool more = (gt + 4 < 49);
    if (more) stage(gt + 4);

    f32x16 s;
#pragma unroll
    for (int r = 0; r < 16; ++r)
      s[r] = ((r < 8) ? bf2f(ubA[r]) : bf2f(ubB[r - 8])) + b2lo;
    __builtin_amdgcn_s_setprio(1);
#pragma unroll
    for (int c = 0; c < 4; ++c) s = mfma32(kf[c], aq[c], s);
    __builtin_amdgcn_s_setprio(0);

    const int ccr = (kfl + 1) * TPF - gt * 32;
    int kfln = kfl;
    float nb2lo = b2lo, nb2hi = b2hi;
    if (more) {
      const u16x8* bp = (const u16x8*)(bP + (size_t)(gt + 4) * 32);
      ubA = bp[0]; ubB = bp[1];
      kfln = ((gt + 4) * 8) / 49;
      nb2lo = b2q[kfln];
      nb2hi = b2q[kfln < 7 ? kfln + 1 : 7];
    }

    if (ccr < 32) {
      const float dlt = b2hi - b2lo;
#pragma unroll
      for (int r = 0; r < 16; ++r)
        s[r] += ((r & 3) + 8 * (r >> 2) + hi4 >= ccr) ? dlt : 0.f;
    }

#pragma unroll
    for (int r = 0; r < 16; ++r) s[r] = EXP2(s[r]);
    float ps;
    {
      float a = (s[0] + s[1]) + (s[2] + s[3]);
      float bb = (s[4] + s[5]) + (s[6] + s[7]);
      float cc = (s[8] + s[9]) + (s[10] + s[11]);
      float dd = (s[12] + s[13]) + (s[14] + s[15]);
      ps = (a + bb) + (cc + dd);
    }
    {
      unsigned int px, py;
      swap32(__builtin_bit_cast(unsigned int, ps),
             __builtin_bit_cast(unsigned int, ps), px, py);
      ps = __builtin_bit_cast(float, px) + __builtin_bit_cast(float, py);
    }
    lrun += ps;

    unsigned int dw[8];
#pragma unroll
    for (int c = 0; c < 8; ++c) dw[c] = pack2(s[2 * c], s[2 * c + 1]);
    unsigned int f0[4], f1[4];
    swap32(dw[0], dw[2], f0[0], f0[2]);
    swap32(dw[1], dw[3], f0[1], f0[3]);
    swap32(dw[4], dw[6], f1[0], f1[2]);
    swap32(dw[5], dw[7], f1[1], f1[3]);
    const bf16x8 F0 = __builtin_bit_cast(bf16x8, *(ulonglong2*)f0);
    const bf16x8 F1 = __builtin_bit_cast(bf16x8, *(ulonglong2*)f1);

    __builtin_amdgcn_s_setprio(1);
    o0 = mfma32(vf0, F0, o0);
    o0 = mfma32(vf1, F1, o0);
    o1 = mfma32(vf2, F0, o1);
    o1 = mfma32(vf3, F1, o1);
    __builtin_amdgcn_s_setprio(0);

    kfl = kfln;
    b2lo = nb2lo;
    b2hi = nb2hi;
  }

  // ---- two-phase merge (R16): phase A = o0 (+l), phase B = o1 (reuses buffer) ---
  __syncthreads();
  float* mrow = mb + (size_t)(wv * 64 + lane) * 17;
#pragma unroll
  for (int r = 0; r < 16; ++r) mrow[r] = o0[r];
  mrow[16] = lrun;
  __syncthreads();
  float L = 0.f;
  if (wv < 2) {
#pragma unroll
    for (int w2 = 0; w2 < 4; ++w2) L += mb[(size_t)(w2 * 64 + lane) * 17 + 16];
  }
  unsigned short* op = aout + (size_t)(b * NTOK + qn) * CDIM + h * 64;
  if (wv == 0) {  // d0-31 from o0 sums
    float acc[16];
#pragma unroll
    for (int r = 0; r < 16; ++r) acc[r] = 0.f;
#pragma unroll
    for (int w2 = 0; w2 < 4; ++w2) {
      const float* rr = mb + (size_t)(w2 * 64 + lane) * 17;
#pragma unroll
      for (int r = 0; r < 16; ++r) acc[r] += rr[r];
    }
    const float rinv = 1.0f / L;
#pragma unroll
    for (int c = 0; c < 8; ++c) {
      const int d0 = 8 * (c >> 1) + 4 * hi + 2 * (c & 1);
      *(unsigned int*)(op + d0) = pack2(acc[2 * c] * rinv, acc[2 * c + 1] * rinv);
    }
  }
  __syncthreads();
#pragma unroll
  for (int r = 0; r < 16; ++r) mrow[r] = o1[r];
  __syncthreads();
  if (wv == 1) {  // d32-63 from o1 sums
    float acc[16];
#pragma unroll
    for (int r = 0; r < 16; ++r) acc[r] = 0.f;
#pragma unroll
    for (int w2 = 0; w2 < 4; ++w2) {
      const float* rr = mb + (size_t)(w2 * 64 + lane) * 17;
#pragma unroll
      for (int r = 0; r < 16; ++r) acc[r] += rr[r];
    }
    const float rinv = 1.0f / L;
#pragma unroll
    for (int c = 0; c < 8; ++c) {
      const int d0 = 8 * (c >> 1) + 4 * hi + 2 * (c & 1);
      *(unsigned int*)(op + 32 + d0) =
          pack2(acc[2 * c] * rinv, acc[2 * c + 1] * rinv);
    }
  }
}

extern "C" void kernel_launch(void* const* d_in, const int* in_sizes, int n_in,
                              void* d_out, int out_size, void* d_ws, size_t ws_size,
                              hipStream_t stream) {
  (void)in_sizes; (void)n_in; (void)out_size; (void)ws_size;
  const float* x        = (const float*)d_in[0];
  const float* qkv_w    = (const float*)d_in[1];
  const float* q_bias   = (const float*)d_in[2];
  const float* v_bias   = (const float*)d_in[3];
  const float* rp_table = (const float*)d_in[4];
  const float* rt_table = (const float*)d_in[5];
  const float* proj_w   = (const float*)d_in[6];
  const float* proj_b   = (const float*)d_in[7];
  const int* rp_index   = (const int*)d_in[8];
  const int* rt_index   = (const int*)d_in[9];

  char* ws = (char*)d_ws;
  unsigned short* qbuf   = (unsigned short*)(ws + 9633792);
  unsigned short* kbuf   = (unsigned short*)(ws + 14450688);
  unsigned short* vtbuf  = (unsigned short*)(ws + 19267584);
  unsigned short* aout   = (unsigned short*)(ws + 24084480);
  unsigned short* biasP  = (unsigned short*)(ws);
  float* bias2           = (float*)(ws + 30247424);

  gemm0_kernel<<<dim3(450 + NHEADS * AREA1 + 1), 512, 0, stream>>>(
      x, qkv_w, q_bias, v_bias, qbuf, kbuf, vtbuf,
      rp_table, rp_index, rt_table, rt_index, biasP, bias2);
  attn_kernel<<<dim3(1176), 256, 0, stream>>>(
      qbuf, kbuf, vtbuf, biasP, bias2, aout);
  gemm_kernel<1, 64, 64, 256, 2, CDIM / 64>
      <<<dim3((CDIM / 64) * (MPAD / 64)), 256, 0, stream>>>(
          nullptr, aout, proj_w, proj_b, nullptr, nullptr, nullptr, nullptr,
          (float*)d_out);
}

// Round 25
// 103.018 us; speedup vs baseline: 1.0405x; 1.0405x over previous
//
#include <hip/hip_runtime.h>
#include <hip/hip_bf16.h>

#define NHEADS 12
#define NFRAMES 8
#define NTOK 1568
#define CDIM 768
#define DHEAD 64
#define BATCH 2
#define MROWS (BATCH * NTOK) /* 3136 */
#define MPAD 3200
#define K3 (3 * CDIM)        /* 2304 */
#define AREA1 197
#define TPF 196
#define LOG2E 1.4426950408889634f

typedef __bf16 bf16x8 __attribute__((ext_vector_type(8)));
typedef float f32x4 __attribute__((ext_vector_type(4)));
typedef float f32x16 __attribute__((ext_vector_type(16)));
typedef unsigned short u16x8 __attribute__((ext_vector_type(8)));

#if __has_builtin(__builtin_amdgcn_exp2f)
#define EXP2(x) __builtin_amdgcn_exp2f(x)
#else
#define EXP2(x) exp2f(x)
#endif

__device__ __forceinline__ unsigned short f2bf(float f) {
  return __builtin_bit_cast(unsigned short, (__bf16)f);
}
__device__ __forceinline__ float bf2f(unsigned short u) {
  unsigned int x = ((unsigned int)u) << 16;
  return __builtin_bit_cast(float, x);
}
__device__ __forceinline__ bf16x8 ld8(const unsigned short* p) {
  return __builtin_bit_cast(bf16x8, *(const u16x8*)p);
}
__device__ __forceinline__ f32x4 mfma16(bf16x8 a, bf16x8 b, f32x4 c) {
  return __builtin_amdgcn_mfma_f32_16x16x32_bf16(a, b, c, 0, 0, 0);
}
__device__ __forceinline__ f32x16 mfma32(bf16x8 a, bf16x8 b, f32x16 c) {
  return __builtin_amdgcn_mfma_f32_32x32x16_bf16(a, b, c, 0, 0, 0);
}
__device__ __forceinline__ unsigned int pack2(float lo, float hi) {
  return ((unsigned int)f2bf(hi) << 16) | (unsigned int)f2bf(lo);
}
__device__ __forceinline__ void swap32(unsigned int a, unsigned int b,
                                       unsigned int& x, unsigned int& y) {
#if __has_builtin(__builtin_amdgcn_permlane32_swap)
  auto r = __builtin_amdgcn_permlane32_swap(a, b, false, false);
  x = r[0]; y = r[1];
#else
  const bool hi = (threadIdx.x & 63) >= 32;
  unsigned int ea = (unsigned int)__shfl_xor((int)a, 32);
  unsigned int eb = (unsigned int)__shfl_xor((int)b, 32);
  x = hi ? eb : a;
  y = hi ? b : ea;
#endif
}
#define GL_LDS(src, dst)                                                    \
  __builtin_amdgcn_global_load_lds(                                         \
      (const __attribute__((address_space(1))) void*)(src),                 \
      (__attribute__((address_space(3))) void*)(dst), 16, 0, 0)

// m204 bijective XCD swizzle for arbitrary nwg
__device__ __forceinline__ int xcd_swz(int lin, int nwg) {
  const int q = nwg >> 3, r = nwg & 7;
  const int xcd = lin & 7, idx = lin >> 3;
  return (xcd < r ? xcd * (q + 1) : r * (q + 1) + (xcd - r) * q) + idx;
}

// ---------------- gemm0 (qkv proj) BK=64 + fused biasP tail (R23, frozen) --------
__global__ __launch_bounds__(512) void gemm0_kernel(
    const float* __restrict__ x,
    const float* __restrict__ qkv_w,
    const float* __restrict__ q_bias,
    const float* __restrict__ v_bias,
    unsigned short* __restrict__ qbuf,
    unsigned short* __restrict__ kbuf,
    unsigned short* __restrict__ vtbuf,
    const float* __restrict__ rpt,
    const int* __restrict__ rpi,
    const float* __restrict__ rtt,
    const int* __restrict__ rti,
    unsigned short* __restrict__ biasP,
    float* __restrict__ bias2) {
  __shared__ __align__(16) char smem[65536];
  unsigned short* As = (unsigned short*)smem;
  unsigned short* Bs = As + 16384;

  if (blockIdx.x >= 450) {  // ---- fused biasP tail ----
    const int bb = blockIdx.x - 450;
    if (bb == NHEADS * AREA1) {
      for (int t = threadIdx.x; t < NHEADS * 64; t += 512) {
        int h = t >> 6, ff = t & 63;
        bias2[t] = rtt[rti[ff] * NHEADS + h] * LOG2E;
      }
      return;
    }
    float* row = (float*)smem;
    const int h = bb / AREA1;
    const int i = bb - h * AREA1;  // qmod
    for (int j = threadIdx.x; j < AREA1; j += 512)
      row[j] = rpt[rpi[i * AREA1 + j] * NHEADS + h] * LOG2E;
    __syncthreads();
    unsigned short* dst = biasP + (size_t)bb * 49 * 32;
    for (int e = threadIdx.x; e < 49 * 32; e += 512) {
      const int t = e >> 5, r = e & 31;
      const int hi = r >> 4, rr = r & 15;
      int km = 32 * t + (rr & 3) + 8 * (rr >> 2) + 4 * hi;
      km %= AREA1;
      dst[e] = f2bf(row[km]);
    }
    return;
  }

  // ---- gemm body ----
  const int lane = threadIdx.x & 63;
  const int wv = threadIdx.x >> 6;  // 0..7
  const int tid = threadIdx.x;
  const int wg = xcd_swz(blockIdx.x, 450);
  const int m0 = (wg / 18) * 128;
  const int n0 = (wg % 18) * 128;

  const int srow = tid >> 3;
  const int srcc = (tid & 7) ^ ((tid >> 3) & 7);
  int ar0 = m0 + srow;      if (ar0 >= MROWS) ar0 = MROWS - 1;
  int ar1 = m0 + 64 + srow; if (ar1 >= MROWS) ar1 = MROWS - 1;
  const int br0 = n0 + srow, br1 = n0 + 64 + srow;

  f32x4 ra[4], rb[4];
  auto issueLoads = [&](int kt) {
    const int k0 = kt * 64 + srcc * 8;
    const f32x4* p;
    p = (const f32x4*)(x + (size_t)ar0 * CDIM + k0);     ra[0] = p[0]; ra[1] = p[1];
    p = (const f32x4*)(x + (size_t)ar1 * CDIM + k0);     ra[2] = p[0]; ra[3] = p[1];
    p = (const f32x4*)(qkv_w + (size_t)br0 * CDIM + k0); rb[0] = p[0]; rb[1] = p[1];
    p = (const f32x4*)(qkv_w + (size_t)br1 * CDIM + k0); rb[2] = p[0]; rb[3] = p[1];
  };
  auto cvt8 = [&](const f32x4& a, const f32x4& b) {
    u16x8 w;
    w[0] = f2bf(a[0]); w[1] = f2bf(a[1]); w[2] = f2bf(a[2]); w[3] = f2bf(a[3]);
    w[4] = f2bf(b[0]); w[5] = f2bf(b[1]); w[6] = f2bf(b[2]); w[7] = f2bf(b[3]);
    return w;
  };
  auto writeStage = [&](int buf) {
    const int o = buf * 8192 + (tid >> 3) * 64 + (tid & 7) * 8;
    *(u16x8*)&As[o]        = cvt8(ra[0], ra[1]);
    *(u16x8*)&As[o + 4096] = cvt8(ra[2], ra[3]);
    *(u16x8*)&Bs[o]        = cvt8(rb[0], rb[1]);
    *(u16x8*)&Bs[o + 4096] = cvt8(rb[2], rb[3]);
  };

  f32x4 acc[2][4] = {};
  const int rbase = (wv & 3) * 32;
  const int cbase = (wv >> 2) * 64;
  const int lc = lane >> 4;

  issueLoads(0);
  __builtin_amdgcn_sched_barrier(0);
  writeStage(0);
  __syncthreads();
  int cur = 0;
  for (int kt = 0; kt < CDIM / 64; ++kt) {
    if (kt + 1 < CDIM / 64) issueLoads(kt + 1);
    __builtin_amdgcn_sched_barrier(0);
#pragma unroll
    for (int s = 0; s < 2; ++s) {
      const int c = s * 4 + lc;
      bf16x8 af[2], bg[4];
#pragma unroll
      for (int i = 0; i < 2; ++i) {
        const int rr = rbase + i * 16 + (lane & 15);
        af[i] = ld8(&As[cur * 8192 + rr * 64 + ((c ^ (rr & 7)) << 3)]);
      }
#pragma unroll
      for (int j = 0; j < 4; ++j) {
        const int rr = cbase + j * 16 + (lane & 15);
        bg[j] = ld8(&Bs[cur * 8192 + rr * 64 + ((c ^ (rr & 7)) << 3)]);
      }
#pragma unroll
      for (int i = 0; i < 2; ++i)
#pragma unroll
        for (int j = 0; j < 4; ++j)
          acc[i][j] = mfma16(af[i], bg[j], acc[i][j]);
    }
    if (kt + 1 < CDIM / 64) writeStage(cur ^ 1);
    __syncthreads();
    cur ^= 1;
  }

#pragma unroll
  for (int i = 0; i < 2; ++i) {
#pragma unroll
    for (int j = 0; j < 4; ++j) {
#pragma unroll
      for (int r = 0; r < 4; ++r) {
        int grow = m0 + rbase + i * 16 + (lane >> 4) * 4 + r;
        int gcol = n0 + cbase + j * 16 + (lane & 15);
        if (grow >= MROWS) continue;
        float v = acc[i][j][r];
        int which = gcol / CDIM;
        int cc = gcol - which * CDIM;
        int hh = cc >> 6, dd = cc & 63;
        int b = grow / NTOK, n = grow - b * NTOK;
        size_t hd = ((size_t)(b * NHEADS + hh) * NTOK + n) * 64 + dd;
        if (which == 0)
          qbuf[hd] = f2bf((v + q_bias[cc]) * (0.125f * LOG2E));
        else if (which == 1)
          kbuf[hd] = f2bf(v);
        else
          vtbuf[((size_t)(b * NHEADS + hh) * 64 + dd) * NTOK + n] =
              f2bf(v + v_bias[cc]);
      }
    }
  }
}

// ---------------- gemm1 (out proj) 128x64xBK64, 512 thr (R25) ----------------
// Same transform that won gemm0 -7.4us in R23: 12 k-steps (was 24), half the
// barriers/exposed windows, 8 MFMA/wave/step. 300 blocks, 48KB LDS -> 3/CU,
// all co-resident. A = aout (bf16) via global_load_lds w/ pre-swizzled source;
// B = proj_w (fp32) reg-converted with the R21 sched_barrier pin. Full 8-key
// XOR swizzle both operands (128B rows = exact bank stripe).
__global__ __launch_bounds__(512) void gemm1_kernel(
    const unsigned short* __restrict__ aout,
    const float* __restrict__ proj_w,
    const float* __restrict__ proj_b,
    float* __restrict__ Cout) {
  __shared__ __align__(16) char smem[49152];
  unsigned short* As = (unsigned short*)smem;   // [2][128*64] = 32KB
  unsigned short* Bs = As + 16384;              // [2][64*64]  = 16KB

  const int lane = threadIdx.x & 63;
  const int wv = threadIdx.x >> 6;  // 0..7
  const int tid = threadIdx.x;
  const int wg = xcd_swz(blockIdx.x, 300);
  const int m0 = (wg / 12) * 128;   // NB_N = CDIM/64 = 12
  const int n0 = (wg % 12) * 64;

  const int srcc = (tid & 7) ^ ((tid >> 3) & 7);  // pre-swizzled logical chunk
  int ar0 = m0 + (tid >> 3);       if (ar0 >= MROWS) ar0 = MROWS - 1;
  int ar1 = m0 + 64 + (tid >> 3);  if (ar1 >= MROWS) ar1 = MROWS - 1;
  const int brow = n0 + (tid >> 3);

  f32x4 rb[2];
  auto issueLoads = [&](int kt, int buf) {
    const int k0 = kt * 64 + srcc * 8;
    GL_LDS(aout + (size_t)ar0 * CDIM + k0, &As[buf * 8192 + tid * 8]);
    GL_LDS(aout + (size_t)ar1 * CDIM + k0, &As[buf * 8192 + 4096 + tid * 8]);
    const f32x4* p = (const f32x4*)(proj_w + (size_t)brow * CDIM + k0);
    rb[0] = p[0]; rb[1] = p[1];
  };
  auto writeStage = [&](int buf) {
    u16x8 w;
    w[0] = f2bf(rb[0][0]); w[1] = f2bf(rb[0][1]); w[2] = f2bf(rb[0][2]);
    w[3] = f2bf(rb[0][3]); w[4] = f2bf(rb[1][0]); w[5] = f2bf(rb[1][1]);
    w[6] = f2bf(rb[1][2]); w[7] = f2bf(rb[1][3]);
    *(u16x8*)&Bs[buf * 4096 + tid * 8] = w;
  };

  f32x4 acc[2][2] = {};
  const int rbase = (wv & 3) * 32;   // WAVES_M=4, WM=32
  const int cbase = (wv >> 2) * 32;  // WAVES_N=2, WN=32
  const int lc = lane >> 4;

  issueLoads(0, 0);
  __builtin_amdgcn_sched_barrier(0);
  writeStage(0);
  __syncthreads();
  int cur = 0;
  for (int kt = 0; kt < CDIM / 64; ++kt) {  // 12 iters
    if (kt + 1 < CDIM / 64) issueLoads(kt + 1, cur ^ 1);
    __builtin_amdgcn_sched_barrier(0);
#pragma unroll
    for (int s = 0; s < 2; ++s) {
      const int c = s * 4 + lc;
      bf16x8 af[2], bg[2];
#pragma unroll
      for (int i = 0; i < 2; ++i) {
        const int rr = rbase + i * 16 + (lane & 15);
        af[i] = ld8(&As[cur * 8192 + rr * 64 + ((c ^ (rr & 7)) << 3)]);
      }
#pragma unroll
      for (int j = 0; j < 2; ++j) {
        const int rr = cbase + j * 16 + (lane & 15);
        bg[j] = ld8(&Bs[cur * 4096 + rr * 64 + ((c ^ (rr & 7)) << 3)]);
      }
#pragma unroll
      for (int i = 0; i < 2; ++i)
#pragma unroll
        for (int j = 0; j < 2; ++j)
          acc[i][j] = mfma16(af[i], bg[j], acc[i][j]);
    }
    if (kt + 1 < CDIM / 64) writeStage(cur ^ 1);
    __syncthreads();
    cur ^= 1;
  }

#pragma unroll
  for (int i = 0; i < 2; ++i) {
#pragma unroll
    for (int j = 0; j < 2; ++j) {
#pragma unroll
      for (int r = 0; r < 4; ++r) {
        int grow = m0 + rbase + i * 16 + (lane >> 4) * 4 + r;
        int gcol = n0 + cbase + j * 16 + (lane & 15);
        if (grow >= MROWS) continue;
        Cout[(size_t)grow * CDIM + gcol] = acc[i][j][r] + proj_b[gcol];
      }
    }
  }
}

// ---------------- flash attention (R23 verbatim — best measured) ----------------
__global__ __launch_bounds__(256) void attn_kernel(
    const unsigned short* __restrict__ qbuf,
    const unsigned short* __restrict__ kbuf,
    const unsigned short* __restrict__ vtbuf,
    const unsigned short* __restrict__ biasP,
    const float* __restrict__ bias2,
    unsigned short* __restrict__ aout) {
  __shared__ __align__(16) char smem[36864];
  unsigned short* stg = (unsigned short*)smem;
  float* mb = (float*)smem;

  const int lane = threadIdx.x & 63;
  const int wv = threadIdx.x >> 6;
  const int wu = (blockIdx.x & 7) * 147 + (blockIdx.x >> 3);
  const int bh = wu / 49;
  const int qt = wu - bh * 49;
  const int q0 = qt * 32;
  const int h = bh % NHEADS;
  const int b = bh / NHEADS;
  const int qlane = lane & 31;
  const int hi = lane >> 5;
  const int hi4 = hi * 4;
  const int qn = q0 + qlane;
  const int qfr = qn / TPF < 7 ? qn / TPF : 7;
  const int qmod = qn % AREA1;

  const unsigned short* qp = qbuf + (size_t)bh * NTOK * DHEAD;
  const unsigned short* kp = kbuf + (size_t)bh * NTOK * DHEAD;
  const unsigned short* vp = vtbuf + (size_t)bh * DHEAD * NTOK;
  const unsigned short* bP = biasP + ((size_t)(h * AREA1 + qmod) * 49) * 32 + hi * 16;
  const float* b2q = bias2 + h * 64 + qfr * 8;

  unsigned short* KsW = stg + wv * 4096;
  unsigned short* VsW = KsW + 2048;

  const unsigned short* ksb =
      kp + (size_t)(lane >> 3) * DHEAD + (((lane & 7) ^ (lane >> 3)) << 3);
  const unsigned short* vsb =
      vp + (size_t)(lane >> 2) * NTOK + (((lane & 3) ^ ((lane >> 3) & 3)) << 3);

  auto stage = [&](int gt) {
    const int kv0 = gt * 32;
#pragma unroll
    for (int j = 0; j < 4; ++j) {
      GL_LDS(ksb + (size_t)(kv0 + j * 8) * DHEAD, KsW + j * 512);
      GL_LDS(vsb + kv0 + (size_t)(j * 16) * NTOK, VsW + j * 512);
    }
  };

  bf16x8 aq[4];
#pragma unroll
  for (int c = 0; c < 4; ++c)
    aq[c] = ld8(qp + (size_t)qn * DHEAD + c * 16 + hi * 8);

  f32x16 o0 = {}, o1 = {};
  float lrun = 0.f;

  stage(wv);
  u16x8 ubA, ubB;
  {
    const u16x8* bp = (const u16x8*)(bP + (size_t)wv * 32);
    ubA = bp[0]; ubB = bp[1];
  }
  int kfl = 0;
  float b2lo = b2q[0], b2hi = b2q[1];
  const int skey = qlane & 7;
  const int vswz = (qlane >> 1) & 3;

  for (int gt = wv; gt < 49; gt += 4) {
    asm volatile("s_waitcnt vmcnt(0)" ::: "memory");
    __builtin_amdgcn_sched_barrier(0);
    bf16x8 kf[4];
#pragma unroll
    for (int c = 0; c < 4; ++c)
      kf[c] = ld8(&KsW[qlane * 64 + ((((c << 1) + hi) ^ skey) << 3)]);
    bf16x8 vf0 = ld8(&VsW[qlane * 32 + ((hi ^ vswz) << 3)]);
    bf16x8 vf1 = ld8(&VsW[qlane * 32 + (((2 + hi) ^ vswz) << 3)]);
    bf16x8 vf2 = ld8(&VsW[(32 + qlane) * 32 + ((hi ^ vswz) << 3)]);
    bf16x8 vf3 = ld8(&VsW[(32 + qlane) * 32 + (((2 + hi) ^ vswz) << 3)]);
    asm volatile("s_waitcnt lgkmcnt(0)" ::: "memory");
    __builtin_amdgcn_sched_barrier(0);
    const bool more = (gt + 4 < 49);
    if (more) stage(gt + 4);

    f32x16 s;
#pragma unroll
    for (int r = 0; r < 16; ++r)
      s[r] = ((r < 8) ? bf2f(ubA[r]) : bf2f(ubB[r - 8])) + b2lo;
    __builtin_amdgcn_s_setprio(1);
#pragma unroll
    for (int c = 0; c < 4; ++c) s = mfma32(kf[c], aq[c], s);
    __builtin_amdgcn_s_setprio(0);

    const int ccr = (kfl + 1) * TPF - gt * 32;
    int kfln = kfl;
    float nb2lo = b2lo, nb2hi = b2hi;
    if (more) {
      const u16x8* bp = (const u16x8*)(bP + (size_t)(gt + 4) * 32);
      ubA = bp[0]; ubB = bp[1];
      kfln = ((gt + 4) * 8) / 49;
      nb2lo = b2q[kfln];
      nb2hi = b2q[kfln < 7 ? kfln + 1 : 7];
    }

    if (ccr < 32) {
      const float dlt = b2hi - b2lo;
#pragma unroll
      for (int r = 0; r < 16; ++r)
        s[r] += ((r & 3) + 8 * (r >> 2) + hi4 >= ccr) ? dlt : 0.f;
    }

#pragma unroll
    for (int r = 0; r < 16; ++r) s[r] = EXP2(s[r]);
    float ps;
    {
      float a = (s[0] + s[1]) + (s[2] + s[3]);
      float bb = (s[4] + s[5]) + (s[6] + s[7]);
      float cc = (s[8] + s[9]) + (s[10] + s[11]);
      float dd = (s[12] + s[13]) + (s[14] + s[15]);
      ps = (a + bb) + (cc + dd);
    }
    {
      unsigned int px, py;
      swap32(__builtin_bit_cast(unsigned int, ps),
             __builtin_bit_cast(unsigned int, ps), px, py);
      ps = __builtin_bit_cast(float, px) + __builtin_bit_cast(float, py);
    }
    lrun += ps;

    unsigned int dw[8];
#pragma unroll
    for (int c = 0; c < 8; ++c) dw[c] = pack2(s[2 * c], s[2 * c + 1]);
    unsigned int f0[4], f1[4];
    swap32(dw[0], dw[2], f0[0], f0[2]);
    swap32(dw[1], dw[3], f0[1], f0[3]);
    swap32(dw[4], dw[6], f1[0], f1[2]);
    swap32(dw[5], dw[7], f1[1], f1[3]);
    const bf16x8 F0 = __builtin_bit_cast(bf16x8, *(ulonglong2*)f0);
    const bf16x8 F1 = __builtin_bit_cast(bf16x8, *(ulonglong2*)f1);

    __builtin_amdgcn_s_setprio(1);
    o0 = mfma32(vf0, F0, o0);
    o0 = mfma32(vf1, F1, o0);
    o1 = mfma32(vf2, F0, o1);
    o1 = mfma32(vf3, F1, o1);
    __builtin_amdgcn_s_setprio(0);

    kfl = kfln;
    b2lo = nb2lo;
    b2hi = nb2hi;
  }

  // ---- merge: plain sums across the 4 waves (no-max) ----
  __syncthreads();
  float* mrow = mb + (size_t)(wv * 64 + lane) * 34;
#pragma unroll
  for (int r = 0; r < 16; ++r) {
    mrow[r] = o0[r];
    mrow[16 + r] = o1[r];
  }
  mrow[32] = lrun;
  __syncthreads();
  if (wv < 2) {
    const int off = wv * 16;
    float acc[16];
#pragma unroll
    for (int r = 0; r < 16; ++r) acc[r] = 0.f;
    float L = 0.f;
#pragma unroll
    for (int w2 = 0; w2 < 4; ++w2) {
      const float* rr = mb + (size_t)(w2 * 64 + lane) * 34;
      L += rr[32];
#pragma unroll
      for (int r = 0; r < 16; ++r) acc[r] += rr[off + r];
    }
    const float rinv = 1.0f / L;
    unsigned short* op = aout + (size_t)(b * NTOK + qn) * CDIM + h * 64 + wv * 32;
#pragma unroll
    for (int c = 0; c < 8; ++c) {
      const int d0 = 8 * (c >> 1) + 4 * hi + 2 * (c & 1);
      *(unsigned int*)(op + d0) = pack2(acc[2 * c] * rinv, acc[2 * c + 1] * rinv);
    }
  }
}

extern "C" void kernel_launch(void* const* d_in, const int* in_sizes, int n_in,
                              void* d_out, int out_size, void* d_ws, size_t ws_size,
                              hipStream_t stream) {
  (void)in_sizes; (void)n_in; (void)out_size; (void)ws_size;
  const float* x        = (const float*)d_in[0];
  const float* qkv_w    = (const float*)d_in[1];
  const float* q_bias   = (const float*)d_in[2];
  const float* v_bias   = (const float*)d_in[3];
  const float* rp_table = (const float*)d_in[4];
  const float* rt_table = (const float*)d_in[5];
  const float* proj_w   = (const float*)d_in[6];
  const float* proj_b   = (const float*)d_in[7];
  const int* rp_index   = (const int*)d_in[8];
  const int* rt_index   = (const int*)d_in[9];

  char* ws = (char*)d_ws;
  unsigned short* qbuf   = (unsigned short*)(ws + 9633792);
  unsigned short* kbuf   = (unsigned short*)(ws + 14450688);
  unsigned short* vtbuf  = (unsigned short*)(ws + 19267584);
  unsigned short* aout   = (unsigned short*)(ws + 24084480);
  unsigned short* biasP  = (unsigned short*)(ws);
  float* bias2           = (float*)(ws + 30247424);

  gemm0_kernel<<<dim3(450 + NHEADS * AREA1 + 1), 512, 0, stream>>>(
      x, qkv_w, q_bias, v_bias, qbuf, kbuf, vtbuf,
      rp_table, rp_index, rt_table, rt_index, biasP, bias2);
  attn_kernel<<<dim3(1176), 256, 0, stream>>>(
      qbuf, kbuf, vtbuf, biasP, bias2, aout);
  gemm1_kernel<<<dim3(300), 512, 0, stream>>>(
      aout, proj_w, proj_b, (float*)d_out);
}

// Round 26
// 102.485 us; speedup vs baseline: 1.0459x; 1.0052x over previous
//
#include <hip/hip_runtime.h>
#include <hip/hip_bf16.h>

#define NHEADS 12
#define NFRAMES 8
#define NTOK 1568
#define CDIM 768
#define DHEAD 64
#define BATCH 2
#define MROWS (BATCH * NTOK) /* 3136 */
#define MPAD 3200
#define K3 (3 * CDIM)        /* 2304 */
#define AREA1 197
#define TPF 196
#define LOG2E 1.4426950408889634f

typedef __bf16 bf16x8 __attribute__((ext_vector_type(8)));
typedef float f32x4 __attribute__((ext_vector_type(4)));
typedef float f32x16 __attribute__((ext_vector_type(16)));
typedef unsigned short u16x8 __attribute__((ext_vector_type(8)));

#if __has_builtin(__builtin_amdgcn_exp2f)
#define EXP2(x) __builtin_amdgcn_exp2f(x)
#else
#define EXP2(x) exp2f(x)
#endif

__device__ __forceinline__ unsigned short f2bf(float f) {
  return __builtin_bit_cast(unsigned short, (__bf16)f);
}
__device__ __forceinline__ float bf2f(unsigned short u) {
  unsigned int x = ((unsigned int)u) << 16;
  return __builtin_bit_cast(float, x);
}
__device__ __forceinline__ bf16x8 ld8(const unsigned short* p) {
  return __builtin_bit_cast(bf16x8, *(const u16x8*)p);
}
__device__ __forceinline__ f32x4 mfma16(bf16x8 a, bf16x8 b, f32x4 c) {
  return __builtin_amdgcn_mfma_f32_16x16x32_bf16(a, b, c, 0, 0, 0);
}
__device__ __forceinline__ f32x16 mfma32(bf16x8 a, bf16x8 b, f32x16 c) {
  return __builtin_amdgcn_mfma_f32_32x32x16_bf16(a, b, c, 0, 0, 0);
}
__device__ __forceinline__ unsigned int pack2(float lo, float hi) {
  return ((unsigned int)f2bf(hi) << 16) | (unsigned int)f2bf(lo);
}
__device__ __forceinline__ void swap32(unsigned int a, unsigned int b,
                                       unsigned int& x, unsigned int& y) {
#if __has_builtin(__builtin_amdgcn_permlane32_swap)
  auto r = __builtin_amdgcn_permlane32_swap(a, b, false, false);
  x = r[0]; y = r[1];
#else
  const bool hi = (threadIdx.x & 63) >= 32;
  unsigned int ea = (unsigned int)__shfl_xor((int)a, 32);
  unsigned int eb = (unsigned int)__shfl_xor((int)b, 32);
  x = hi ? eb : a;
  y = hi ? b : ea;
#endif
}
#define GL_LDS(src, dst)                                                    \
  __builtin_amdgcn_global_load_lds(                                         \
      (const __attribute__((address_space(1))) void*)(src),                 \
      (__attribute__((address_space(3))) void*)(dst), 16, 0, 0)

// m204 bijective XCD swizzle for arbitrary nwg
__device__ __forceinline__ int xcd_swz(int lin, int nwg) {
  const int q = nwg >> 3, r = nwg & 7;
  const int xcd = lin & 7, idx = lin >> 3;
  return (xcd < r ? xcd * (q + 1) : r * (q + 1) + (xcd - r) * q) + idx;
}

// ---------------- gemm0 (qkv proj) BK=64, mfma32 compute + fused biasP tail ------
// R26: inner compute 16 mfma16 -> 4 mfma32 chains (2 acc x 4 k-chunks): LDS
// reads 16 -> 12 b128/wave/k-step (A:4, B:8; the dominant pipe demand, -25%),
// MFMA issue 77.6 -> 64.6 cy, fewer instrs. Fragment layouts = the 32x32 maps
// HW-validated in attn (A/B: row/col=lane&31, k=(lane>>5)*8+j; C/D: row=
// (r&3)+8*(r>>2)+4*(lane>>5), col=lane&31). Swizzled reads stay bank-balanced
// (32 rows x 2 chunks, 8 accesses/4-bank group = b128 floor).
__global__ __launch_bounds__(512) void gemm0_kernel(
    const float* __restrict__ x,
    const float* __restrict__ qkv_w,
    const float* __restrict__ q_bias,
    const float* __restrict__ v_bias,
    unsigned short* __restrict__ qbuf,
    unsigned short* __restrict__ kbuf,
    unsigned short* __restrict__ vtbuf,
    const float* __restrict__ rpt,
    const int* __restrict__ rpi,
    const float* __restrict__ rtt,
    const int* __restrict__ rti,
    unsigned short* __restrict__ biasP,
    float* __restrict__ bias2) {
  __shared__ __align__(16) char smem[65536];
  unsigned short* As = (unsigned short*)smem;
  unsigned short* Bs = As + 16384;

  if (blockIdx.x >= 450) {  // ---- fused biasP tail ----
    const int bb = blockIdx.x - 450;
    if (bb == NHEADS * AREA1) {
      for (int t = threadIdx.x; t < NHEADS * 64; t += 512) {
        int h = t >> 6, ff = t & 63;
        bias2[t] = rtt[rti[ff] * NHEADS + h] * LOG2E;
      }
      return;
    }
    float* row = (float*)smem;
    const int h = bb / AREA1;
    const int i = bb - h * AREA1;  // qmod
    for (int j = threadIdx.x; j < AREA1; j += 512)
      row[j] = rpt[rpi[i * AREA1 + j] * NHEADS + h] * LOG2E;
    __syncthreads();
    unsigned short* dst = biasP + (size_t)bb * 49 * 32;
    for (int e = threadIdx.x; e < 49 * 32; e += 512) {
      const int t = e >> 5, r = e & 31;
      const int hi = r >> 4, rr = r & 15;
      int km = 32 * t + (rr & 3) + 8 * (rr >> 2) + 4 * hi;
      km %= AREA1;
      dst[e] = f2bf(row[km]);
    }
    return;
  }

  // ---- gemm body ----
  const int lane = threadIdx.x & 63;
  const int wv = threadIdx.x >> 6;  // 0..7
  const int tid = threadIdx.x;
  const int wg = xcd_swz(blockIdx.x, 450);
  const int m0 = (wg / 18) * 128;
  const int n0 = (wg % 18) * 128;

  const int srow = tid >> 3;
  const int srcc = (tid & 7) ^ ((tid >> 3) & 7);
  int ar0 = m0 + srow;      if (ar0 >= MROWS) ar0 = MROWS - 1;
  int ar1 = m0 + 64 + srow; if (ar1 >= MROWS) ar1 = MROWS - 1;
  const int br0 = n0 + srow, br1 = n0 + 64 + srow;

  f32x4 ra[4], rb[4];
  auto issueLoads = [&](int kt) {
    const int k0 = kt * 64 + srcc * 8;
    const f32x4* p;
    p = (const f32x4*)(x + (size_t)ar0 * CDIM + k0);     ra[0] = p[0]; ra[1] = p[1];
    p = (const f32x4*)(x + (size_t)ar1 * CDIM + k0);     ra[2] = p[0]; ra[3] = p[1];
    p = (const f32x4*)(qkv_w + (size_t)br0 * CDIM + k0); rb[0] = p[0]; rb[1] = p[1];
    p = (const f32x4*)(qkv_w + (size_t)br1 * CDIM + k0); rb[2] = p[0]; rb[3] = p[1];
  };
  auto cvt8 = [&](const f32x4& a, const f32x4& b) {
    u16x8 w;
    w[0] = f2bf(a[0]); w[1] = f2bf(a[1]); w[2] = f2bf(a[2]); w[3] = f2bf(a[3]);
    w[4] = f2bf(b[0]); w[5] = f2bf(b[1]); w[6] = f2bf(b[2]); w[7] = f2bf(b[3]);
    return w;
  };
  auto writeStage = [&](int buf) {
    const int o = buf * 8192 + (tid >> 3) * 64 + (tid & 7) * 8;
    *(u16x8*)&As[o]        = cvt8(ra[0], ra[1]);
    *(u16x8*)&As[o + 4096] = cvt8(ra[2], ra[3]);
    *(u16x8*)&Bs[o]        = cvt8(rb[0], rb[1]);
    *(u16x8*)&Bs[o + 4096] = cvt8(rb[2], rb[3]);
  };

  f32x16 acc0 = {}, acc1 = {};       // two 32-col n-tiles
  const int rbase = (wv & 3) * 32;   // WAVES_M=4, WM=32
  const int cbase = (wv >> 2) * 64;  // WAVES_N=2, WN=64
  const int hi = lane >> 5;
  const int ra32 = rbase + (lane & 31);        // A row for mfma32 frag
  const int cb0 = cbase + (lane & 31);         // B cols
  const int cb1 = cbase + 32 + (lane & 31);

  issueLoads(0);
  __builtin_amdgcn_sched_barrier(0);
  writeStage(0);
  __syncthreads();
  int cur = 0;
  for (int kt = 0; kt < CDIM / 64; ++kt) {
    if (kt + 1 < CDIM / 64) issueLoads(kt + 1);
    __builtin_amdgcn_sched_barrier(0);
#pragma unroll
    for (int c2 = 0; c2 < 4; ++c2) {       // four k=16 sub-steps
      const int ck = c2 * 2 + hi;          // 8-elem chunk 0..7
      bf16x8 af = ld8(&As[cur * 8192 + ra32 * 64 + ((ck ^ (ra32 & 7)) << 3)]);
      bf16x8 bg0 = ld8(&Bs[cur * 8192 + cb0 * 64 + ((ck ^ (cb0 & 7)) << 3)]);
      bf16x8 bg1 = ld8(&Bs[cur * 8192 + cb1 * 64 + ((ck ^ (cb1 & 7)) << 3)]);
      acc0 = mfma32(af, bg0, acc0);
      acc1 = mfma32(af, bg1, acc1);
    }
    if (kt + 1 < CDIM / 64) writeStage(cur ^ 1);
    __syncthreads();
    cur ^= 1;
  }

  // epilogue: 32x32 C/D map (row=(r&3)+8*(r>>2)+4*hi, col=lane&31)
#pragma unroll
  for (int j = 0; j < 2; ++j) {
    const f32x16& ac = j ? acc1 : acc0;
#pragma unroll
    for (int r = 0; r < 16; ++r) {
      int grow = m0 + rbase + (r & 3) + 8 * (r >> 2) + 4 * hi;
      int gcol = n0 + cbase + j * 32 + (lane & 31);
      if (grow >= MROWS) continue;
      float v = ac[r];
      int which = gcol / CDIM;
      int cc = gcol - which * CDIM;
      int hh = cc >> 6, dd = cc & 63;
      int b = grow / NTOK, n = grow - b * NTOK;
      size_t hd = ((size_t)(b * NHEADS + hh) * NTOK + n) * 64 + dd;
      if (which == 0)
        qbuf[hd] = f2bf((v + q_bias[cc]) * (0.125f * LOG2E));
      else if (which == 1)
        kbuf[hd] = f2bf(v);
      else
        vtbuf[((size_t)(b * NHEADS + hh) * 64 + dd) * NTOK + n] =
            f2bf(v + v_bias[cc]);
    }
  }
}

// ---------------- gemm1 (out proj) 128x64xBK64, 512 thr (R25, frozen) ------------
__global__ __launch_bounds__(512) void gemm1_kernel(
    const unsigned short* __restrict__ aout,
    const float* __restrict__ proj_w,
    const float* __restrict__ proj_b,
    float* __restrict__ Cout) {
  __shared__ __align__(16) char smem[49152];
  unsigned short* As = (unsigned short*)smem;   // [2][128*64] = 32KB
  unsigned short* Bs = As + 16384;              // [2][64*64]  = 16KB

  const int lane = threadIdx.x & 63;
  const int wv = threadIdx.x >> 6;  // 0..7
  const int tid = threadIdx.x;
  const int wg = xcd_swz(blockIdx.x, 300);
  const int m0 = (wg / 12) * 128;   // NB_N = CDIM/64 = 12
  const int n0 = (wg % 12) * 64;

  const int srcc = (tid & 7) ^ ((tid >> 3) & 7);  // pre-swizzled logical chunk
  int ar0 = m0 + (tid >> 3);       if (ar0 >= MROWS) ar0 = MROWS - 1;
  int ar1 = m0 + 64 + (tid >> 3);  if (ar1 >= MROWS) ar1 = MROWS - 1;
  const int brow = n0 + (tid >> 3);

  f32x4 rb[2];
  auto issueLoads = [&](int kt, int buf) {
    const int k0 = kt * 64 + srcc * 8;
    GL_LDS(aout + (size_t)ar0 * CDIM + k0, &As[buf * 8192 + tid * 8]);
    GL_LDS(aout + (size_t)ar1 * CDIM + k0, &As[buf * 8192 + 4096 + tid * 8]);
    const f32x4* p = (const f32x4*)(proj_w + (size_t)brow * CDIM + k0);
    rb[0] = p[0]; rb[1] = p[1];
  };
  auto writeStage = [&](int buf) {
    u16x8 w;
    w[0] = f2bf(rb[0][0]); w[1] = f2bf(rb[0][1]); w[2] = f2bf(rb[0][2]);
    w[3] = f2bf(rb[0][3]); w[4] = f2bf(rb[1][0]); w[5] = f2bf(rb[1][1]);
    w[6] = f2bf(rb[1][2]); w[7] = f2bf(rb[1][3]);
    *(u16x8*)&Bs[buf * 4096 + tid * 8] = w;
  };

  f32x4 acc[2][2] = {};
  const int rbase = (wv & 3) * 32;   // WAVES_M=4, WM=32
  const int cbase = (wv >> 2) * 32;  // WAVES_N=2, WN=32
  const int lc = lane >> 4;

  issueLoads(0, 0);
  __builtin_amdgcn_sched_barrier(0);
  writeStage(0);
  __syncthreads();
  int cur = 0;
  for (int kt = 0; kt < CDIM / 64; ++kt) {  // 12 iters
    if (kt + 1 < CDIM / 64) issueLoads(kt + 1, cur ^ 1);
    __builtin_amdgcn_sched_barrier(0);
#pragma unroll
    for (int s = 0; s < 2; ++s) {
      const int c = s * 4 + lc;
      bf16x8 af[2], bg[2];
#pragma unroll
      for (int i = 0; i < 2; ++i) {
        const int rr = rbase + i * 16 + (lane & 15);
        af[i] = ld8(&As[cur * 8192 + rr * 64 + ((c ^ (rr & 7)) << 3)]);
      }
#pragma unroll
      for (int j = 0; j < 2; ++j) {
        const int rr = cbase + j * 16 + (lane & 15);
        bg[j] = ld8(&Bs[cur * 4096 + rr * 64 + ((c ^ (rr & 7)) << 3)]);
      }
#pragma unroll
      for (int i = 0; i < 2; ++i)
#pragma unroll
        for (int j = 0; j < 2; ++j)
          acc[i][j] = mfma16(af[i], bg[j], acc[i][j]);
    }
    if (kt + 1 < CDIM / 64) writeStage(cur ^ 1);
    __syncthreads();
    cur ^= 1;
  }

#pragma unroll
  for (int i = 0; i < 2; ++i) {
#pragma unroll
    for (int j = 0; j < 2; ++j) {
#pragma unroll
      for (int r = 0; r < 4; ++r) {
        int grow = m0 + rbase + i * 16 + (lane >> 4) * 4 + r;
        int gcol = n0 + cbase + j * 16 + (lane & 15);
        if (grow >= MROWS) continue;
        Cout[(size_t)grow * CDIM + gcol] = acc[i][j][r] + proj_b[gcol];
      }
    }
  }
}

// ---------------- flash attention (R23 verbatim — best measured) ----------------
__global__ __launch_bounds__(256) void attn_kernel(
    const unsigned short* __restrict__ qbuf,
    const unsigned short* __restrict__ kbuf,
    const unsigned short* __restrict__ vtbuf,
    const unsigned short* __restrict__ biasP,
    const float* __restrict__ bias2,
    unsigned short* __restrict__ aout) {
  __shared__ __align__(16) char smem[36864];
  unsigned short* stg = (unsigned short*)smem;
  float* mb = (float*)smem;

  const int lane = threadIdx.x & 63;
  const int wv = threadIdx.x >> 6;
  const int wu = (blockIdx.x & 7) * 147 + (blockIdx.x >> 3);
  const int bh = wu / 49;
  const int qt = wu - bh * 49;
  const int q0 = qt * 32;
  const int h = bh % NHEADS;
  const int b = bh / NHEADS;
  const int qlane = lane & 31;
  const int hi = lane >> 5;
  const int hi4 = hi * 4;
  const int qn = q0 + qlane;
  const int qfr = qn / TPF < 7 ? qn / TPF : 7;
  const int qmod = qn % AREA1;

  const unsigned short* qp = qbuf + (size_t)bh * NTOK * DHEAD;
  const unsigned short* kp = kbuf + (size_t)bh * NTOK * DHEAD;
  const unsigned short* vp = vtbuf + (size_t)bh * DHEAD * NTOK;
  const unsigned short* bP = biasP + ((size_t)(h * AREA1 + qmod) * 49) * 32 + hi * 16;
  const float* b2q = bias2 + h * 64 + qfr * 8;

  unsigned short* KsW = stg + wv * 4096;
  unsigned short* VsW = KsW + 2048;

  const unsigned short* ksb =
      kp + (size_t)(lane >> 3) * DHEAD + (((lane & 7) ^ (lane >> 3)) << 3);
  const unsigned short* vsb =
      vp + (size_t)(lane >> 2) * NTOK + (((lane & 3) ^ ((lane >> 3) & 3)) << 3);

  auto stage = [&](int gt) {
    const int kv0 = gt * 32;
#pragma unroll
    for (int j = 0; j < 4; ++j) {
      GL_LDS(ksb + (size_t)(kv0 + j * 8) * DHEAD, KsW + j * 512);
      GL_LDS(vsb + kv0 + (size_t)(j * 16) * NTOK, VsW + j * 512);
    }
  };

  bf16x8 aq[4];
#pragma unroll
  for (int c = 0; c < 4; ++c)
    aq[c] = ld8(qp + (size_t)qn * DHEAD + c * 16 + hi * 8);

  f32x16 o0 = {}, o1 = {};
  float lrun = 0.f;

  stage(wv);
  u16x8 ubA, ubB;
  {
    const u16x8* bp = (const u16x8*)(bP + (size_t)wv * 32);
    ubA = bp[0]; ubB = bp[1];
  }
  int kfl = 0;
  float b2lo = b2q[0], b2hi = b2q[1];
  const int skey = qlane & 7;
  const int vswz = (qlane >> 1) & 3;

  for (int gt = wv; gt < 49; gt += 4) {
    asm volatile("s_waitcnt vmcnt(0)" ::: "memory");
    __builtin_amdgcn_sched_barrier(0);
    bf16x8 kf[4];
#pragma unroll
    for (int c = 0; c < 4; ++c)
      kf[c] = ld8(&KsW[qlane * 64 + ((((c << 1) + hi) ^ skey) << 3)]);
    bf16x8 vf0 = ld8(&VsW[qlane * 32 + ((hi ^ vswz) << 3)]);
    bf16x8 vf1 = ld8(&VsW[qlane * 32 + (((2 + hi) ^ vswz) << 3)]);
    bf16x8 vf2 = ld8(&VsW[(32 + qlane) * 32 + ((hi ^ vswz) << 3)]);
    bf16x8 vf3 = ld8(&VsW[(32 + qlane) * 32 + (((2 + hi) ^ vswz) << 3)]);
    asm volatile("s_waitcnt lgkmcnt(0)" ::: "memory");
    __builtin_amdgcn_sched_barrier(0);
    const bool more = (gt + 4 < 49);
    if (more) stage(gt + 4);

    f32x16 s;
#pragma unroll
    for (int r = 0; r < 16; ++r)
      s[r] = ((r < 8) ? bf2f(ubA[r]) : bf2f(ubB[r - 8])) + b2lo;
    __builtin_amdgcn_s_setprio(1);
#pragma unroll
    for (int c = 0; c < 4; ++c) s = mfma32(kf[c], aq[c], s);
    __builtin_amdgcn_s_setprio(0);

    const int ccr = (kfl + 1) * TPF - gt * 32;
    int kfln = kfl;
    float nb2lo = b2lo, nb2hi = b2hi;
    if (more) {
      const u16x8* bp = (const u16x8*)(bP + (size_t)(gt + 4) * 32);
      ubA = bp[0]; ubB = bp[1];
      kfln = ((gt + 4) * 8) / 49;
      nb2lo = b2q[kfln];
      nb2hi = b2q[kfln < 7 ? kfln + 1 : 7];
    }

    if (ccr < 32) {
      const float dlt = b2hi - b2lo;
#pragma unroll
      for (int r = 0; r < 16; ++r)
        s[r] += ((r & 3) + 8 * (r >> 2) + hi4 >= ccr) ? dlt : 0.f;
    }

#pragma unroll
    for (int r = 0; r < 16; ++r) s[r] = EXP2(s[r]);
    float ps;
    {
      float a = (s[0] + s[1]) + (s[2] + s[3]);
      float bb = (s[4] + s[5]) + (s[6] + s[7]);
      float cc = (s[8] + s[9]) + (s[10] + s[11]);
      float dd = (s[12] + s[13]) + (s[14] + s[15]);
      ps = (a + bb) + (cc + dd);
    }
    {
      unsigned int px, py;
      swap32(__builtin_bit_cast(unsigned int, ps),
             __builtin_bit_cast(unsigned int, ps), px, py);
      ps = __builtin_bit_cast(float, px) + __builtin_bit_cast(float, py);
    }
    lrun += ps;

    unsigned int dw[8];
#pragma unroll
    for (int c = 0; c < 8; ++c) dw[c] = pack2(s[2 * c], s[2 * c + 1]);
    unsigned int f0[4], f1[4];
    swap32(dw[0], dw[2], f0[0], f0[2]);
    swap32(dw[1], dw[3], f0[1], f0[3]);
    swap32(dw[4], dw[6], f1[0], f1[2]);
    swap32(dw[5], dw[7], f1[1], f1[3]);
    const bf16x8 F0 = __builtin_bit_cast(bf16x8, *(ulonglong2*)f0);
    const bf16x8 F1 = __builtin_bit_cast(bf16x8, *(ulonglong2*)f1);

    __builtin_amdgcn_s_setprio(1);
    o0 = mfma32(vf0, F0, o0);
    o0 = mfma32(vf1, F1, o0);
    o1 = mfma32(vf2, F0, o1);
    o1 = mfma32(vf3, F1, o1);
    __builtin_amdgcn_s_setprio(0);

    kfl = kfln;
    b2lo = nb2lo;
    b2hi = nb2hi;
  }

  // ---- merge: plain sums across the 4 waves (no-max) ----
  __syncthreads();
  float* mrow = mb + (size_t)(wv * 64 + lane) * 34;
#pragma unroll
  for (int r = 0; r < 16; ++r) {
    mrow[r] = o0[r];
    mrow[16 + r] = o1[r];
  }
  mrow[32] = lrun;
  __syncthreads();
  if (wv < 2) {
    const int off = wv * 16;
    float acc[16];
#pragma unroll
    for (int r = 0; r < 16; ++r) acc[r] = 0.f;
    float L = 0.f;
#pragma unroll
    for (int w2 = 0; w2 < 4; ++w2) {
      const float* rr = mb + (size_t)(w2 * 64 + lane) * 34;
      L += rr[32];
#pragma unroll
      for (int r = 0; r < 16; ++r) acc[r] += rr[off + r];
    }
    const float rinv = 1.0f / L;
    unsigned short* op = aout + (size_t)(b * NTOK + qn) * CDIM + h * 64 + wv * 32;
#pragma unroll
    for (int c = 0; c < 8; ++c) {
      const int d0 = 8 * (c >> 1) + 4 * hi + 2 * (c & 1);
      *(unsigned int*)(op + d0) = pack2(acc[2 * c] * rinv, acc[2 * c + 1] * rinv);
    }
  }
}

extern "C" void kernel_launch(void* const* d_in, const int* in_sizes, int n_in,
                              void* d_out, int out_size, void* d_ws, size_t ws_size,
                              hipStream_t stream) {
  (void)in_sizes; (void)n_in; (void)out_size; (void)ws_size;
  const float* x        = (const float*)d_in[0];
  const float* qkv_w    = (const float*)d_in[1];
  const float* q_bias   = (const float*)d_in[2];
  const float* v_bias   = (const float*)d_in[3];
  const float* rp_table = (const float*)d_in[4];
  const float* rt_table = (const float*)d_in[5];
  const float* proj_w   = (const float*)d_in[6];
  const float* proj_b   = (const float*)d_in[7];
  const int* rp_index   = (const int*)d_in[8];
  const int* rt_index   = (const int*)d_in[9];

  char* ws = (char*)d_ws;
  unsigned short* qbuf   = (unsigned short*)(ws + 9633792);
  unsigned short* kbuf   = (unsigned short*)(ws + 14450688);
  unsigned short* vtbuf  = (unsigned short*)(ws + 19267584);
  unsigned short* aout   = (unsigned short*)(ws + 24084480);
  unsigned short* biasP  = (unsigned short*)(ws);
  float* bias2           = (float*)(ws + 30247424);

  gemm0_kernel<<<dim3(450 + NHEADS * AREA1 + 1), 512, 0, stream>>>(
      x, qkv_w, q_bias, v_bias, qbuf, kbuf, vtbuf,
      rp_table, rp_index, rt_table, rt_index, biasP, bias2);
  attn_kernel<<<dim3(1176), 256, 0, stream>>>(
      qbuf, kbuf, vtbuf, biasP, bias2, aout);
  gemm1_kernel<<<dim3(300), 512, 0, stream>>>(
      aout, proj_w, proj_b, (float*)d_out);
}